// Round 2
// baseline (314.949 us; speedup 1.0000x reference)
//
#include <hip/hip_runtime.h>
#include <math.h>

#define Tt 250
#define TnN 243
#define Nn 256
#define EPS_ 1e-5f
#define LOG2E 1.44269504f

typedef unsigned short u16;
typedef __bf16 bf16x8 __attribute__((ext_vector_type(8)));
typedef float f32x4 __attribute__((ext_vector_type(4)));

__device__ __forceinline__ u16 f2bf(float f) {
    unsigned u = __builtin_bit_cast(unsigned, f);
    u += 0x7FFFu + ((u >> 16) & 1u);
    return (u16)(u >> 16);
}
__device__ __forceinline__ float bf2f(u16 s) {
    unsigned u = ((unsigned)s) << 16;
    return __builtin_bit_cast(float, u);
}
__device__ __forceinline__ float hw_exp2(float x) {
    return __builtin_amdgcn_exp2f(x);
}

__device__ __forceinline__ void async_load16(const void* g, void* l) {
    __builtin_amdgcn_global_load_lds(
        (const __attribute__((address_space(1))) unsigned int*)g,
        (__attribute__((address_space(3))) unsigned int*)l, 16, 0, 0);
}

// DMA one 15,552 B plane (243x32 u16) global->LDS, 8 waves cooperate
__device__ __forceinline__ void dma_plane(const u16* gsrc, u16* ldst, int w, int lane) {
    const char* g = (const char*)gsrc;
    char* l = (char*)ldst;
    for (int off = w * 1024; off < 15552; off += 8192) {
        int rem = 15552 - off;
        int lim = rem < 1024 ? rem : 1024;
        if (lane * 16 < lim) async_load16(g + off + lane * 16, l + off);
    }
}

// extract ushorts [S..S+7] from a 16-ushort window (two uint4), all static
template<int S>
__device__ __forceinline__ uint4 extract8(const uint4& a, const uint4& b) {
    const unsigned W[8] = {a.x, a.y, a.z, a.w, b.x, b.y, b.z, b.w};
    uint4 r;
    constexpr int i = S >> 1;
    if constexpr ((S & 1) == 0) {
        r.x = W[i]; r.y = W[i + 1]; r.z = W[i + 2]; r.w = W[i + 3];
    } else {
        r.x = (W[i] >> 16)     | (W[i + 1] << 16);
        r.y = (W[i + 1] >> 16) | (W[i + 2] << 16);
        r.z = (W[i + 2] >> 16) | (W[i + 3] << 16);
        r.w = (W[i + 3] >> 16) | (W[i + 4] << 16);
    }
    return r;
}

// serial c-chain over one transposed row pair, direction D compile-time:
// all vector extracts/inserts static -> registers only, no scratch.
template<int D>
__device__ __forceinline__ void chain_run(u16* Zr, u16* Fr, float kf, float bf_) {
    bf16x8 z8 = *(const bf16x8*)&Zr[D ? 240 : 0];
    bf16x8 f8 = *(const bf16x8*)&Fr[D ? 240 : 0];
    float c = 0.f;
    for (int grp = 0; grp < 31; ++grp) {
        int gb = D ? (30 - grp) * 8 : grp * 8;
        bf16x8 zn = z8, fn = f8;
        if (grp < 30) {
            int gbn = D ? (29 - grp) * 8 : (grp + 1) * 8;
            zn = *(const bf16x8*)&Zr[gbn];
            fn = *(const bf16x8*)&Fr[gbn];
        }
        bf16x8 co;
        #pragma unroll
        for (int k = 0; k < 8; ++k) {
            const int idx = D ? (7 - k) : k;     // constexpr after unroll
            int t = gb + idx;
            float uz = (float)z8[idx];
            float af = -LOG2E * ((float)f8[idx] + bf_);
            float xe = fmaf(kf, c, af);
            float fg = __builtin_amdgcn_rcpf(1.f + hw_exp2(xe));
            float cn = fmaf(fg, c - uz, uz);
            bool ok = (t < TnN);
            if (ok) c = cn;
            co[idx] = ok ? (__bf16)c : (__bf16)0.f;
        }
        *(bf16x8*)&Zr[gb] = co;
        z8 = zn; f8 = fn;
    }
}

// ---------------- stats ----------------
__global__ void k_stats(const float* __restrict__ x, float* __restrict__ stats) {
    int b = blockIdx.y;
    const float* xb = x + (size_t)b * 64 * 128 * Tt;
    const int n = 64 * 128 * Tt;
    float s = 0.f, s2 = 0.f;
    for (int i = blockIdx.x * blockDim.x + threadIdx.x; i < n; i += gridDim.x * blockDim.x) {
        float v = xb[i];
        s += v; s2 += v * v;
    }
    for (int off = 32; off; off >>= 1) {
        s  += __shfl_down(s, off);
        s2 += __shfl_down(s2, off);
    }
    __shared__ float ls[8], ls2[8];
    int lane = threadIdx.x & 63, w = threadIdx.x >> 6;
    if (lane == 0) { ls[w] = s; ls2[w] = s2; }
    __syncthreads();
    if (threadIdx.x == 0) {
        float a = 0.f, a2 = 0.f;
        int nw = blockDim.x >> 6;
        for (int i = 0; i < nw; i++) { a += ls[i]; a2 += ls2[i]; }
        atomicAdd(&stats[b * 2 + 0], a);
        atomicAdd(&stats[b * 2 + 1], a2);
    }
}

// ---------------- normalize -> bf16 [n][c][256] ----------------
__global__ void k_norm(const float* __restrict__ x, const float* __restrict__ stats,
                       const float* __restrict__ gamma, const float* __restrict__ beta,
                       u16* __restrict__ xu) {
    int idx = blockIdx.x * blockDim.x + threadIdx.x;
    const int total = Nn * 64 * Tt;
    if (idx >= total) return;
    int t = idx % Tt;
    int c = (idx / Tt) & 63;
    int n = idx / (Tt * 64);
    int b = n >> 7, f = n & 127;
    const float inv = 1.0f / (float)(64 * 128 * Tt);
    float mean = stats[b * 2 + 0] * inv;
    float var  = stats[b * 2 + 1] * inv - mean * mean;
    float rstd = rsqrtf(var + EPS_);
    float v = x[(((size_t)(b * 64 + c)) * 128 + f) * Tt + t];
    xu[((size_t)(n * 64 + c) << 8) + t] = f2bf((v - mean) * rstd * gamma[c] + beta[c]);
}

// ---------------- pack weights ----------------
__global__ void k_packw(const float* __restrict__ W0, const float* __restrict__ Wr,
                        const float* __restrict__ wct,
                        u16* __restrict__ W0t, u16* __restrict__ Wrt, u16* __restrict__ Wcto) {
    int idx = blockIdx.x * blockDim.x + threadIdx.x;
    if (idx < 131072) {
        int j = idx >> 9, p = idx & 511;
        W0t[idx] = f2bf(W0[(size_t)(j >> 7) * 65536 + p * 128 + (j & 127)]);
    } else if (idx < 180224) {
        int r = idx - 131072;
        int i = r & 63, j = (r >> 6) & 255, lidx = r >> 14;
        Wrt[r] = f2bf(Wr[(size_t)(lidx * 2 + (j >> 7)) * 8192 + i * 128 + (j & 127)]);
    } else if (idx < 212992) {
        int r = idx - 180224;
        int o = r >> 9; int k = r & 511; int kk = k >> 6, ci = k & 63;
        Wcto[r] = f2bf(wct[(size_t)ci * 512 + o * 8 + kk]);
    }
}

// ---------------- MFMA GEMM layer 0 (fused im2col) -> U2 [n][d][g][243][32] ----------------
// A[m=(t,n)][c*8+k] = xu_bf[n][c][t+k], staged per-kc from the 8.4MB L2-resident tensor.
__global__ __launch_bounds__(256) void k_gemm0m(const u16* __restrict__ Xb,
                                                const u16* __restrict__ B,
                                                u16* __restrict__ U2) {
    __shared__ u16 sh[16384];
    u16* As = sh;
    const int tid = threadIdx.x;
    const int t = blockIdx.x >> 1;
    const int n0 = (blockIdx.x & 1) * 128;
    const int j0 = blockIdx.y * 128;
    const int d = blockIdx.y;
    const int lane = tid & 63, w = tid >> 6;
    const int wr = w >> 1, wc = w & 1;
    const int ml = lane & 15, q = lane >> 4;
    const int ta = t & ~7, shv = t & 7;     // block-uniform shift
    f32x4 acc[4][4] = {};
    for (int kc = 0; kc < 16; ++kc) {
        int c0 = kc * 32;
        #pragma unroll
        for (int i = 0; i < 2; ++i) {
            int task = tid + i * 256;
            int row = task >> 2, cl = task & 3;
            const u16* src = &Xb[((size_t)((n0 + row) * 64 + kc * 4 + cl) << 8) + ta];
            uint4 L0 = *(const uint4*)src;
            uint4 L1 = *(const uint4*)(src + 8);
            uint4 ov;
            switch (shv) {
                case 0:  ov = extract8<0>(L0, L1); break;
                case 1:  ov = extract8<1>(L0, L1); break;
                case 2:  ov = extract8<2>(L0, L1); break;
                case 3:  ov = extract8<3>(L0, L1); break;
                case 4:  ov = extract8<4>(L0, L1); break;
                case 5:  ov = extract8<5>(L0, L1); break;
                case 6:  ov = extract8<6>(L0, L1); break;
                default: ov = extract8<7>(L0, L1); break;
            }
            *(uint4*)&As[row * 40 + cl * 8] = ov;
        }
        __syncthreads();
        bf16x8 af[4], bfv[4];
        #pragma unroll
        for (int nt = 0; nt < 4; ++nt)
            bfv[nt] = *(const bf16x8*)&B[(size_t)(j0 + wc * 64 + nt * 16 + ml) * 512 + c0 + q * 8];
        #pragma unroll
        for (int mt = 0; mt < 4; ++mt) af[mt] = *(const bf16x8*)&As[(wr * 64 + mt * 16 + ml) * 40 + q * 8];
        #pragma unroll
        for (int mt = 0; mt < 4; ++mt)
            #pragma unroll
            for (int nt = 0; nt < 4; ++nt)
                acc[mt][nt] = __builtin_amdgcn_mfma_f32_16x16x32_bf16(af[mt], bfv[nt], acc[mt][nt], 0, 0, 0);
        __syncthreads();
    }
    u16* Cw = sh + w * 4096;
    #pragma unroll
    for (int mt = 0; mt < 4; ++mt)
        #pragma unroll
        for (int nt = 0; nt < 4; ++nt)
            #pragma unroll
            for (int r = 0; r < 4; ++r)
                Cw[(mt * 16 + q * 4 + r) * 64 + nt * 16 + ml] = f2bf(acc[mt][nt][r]);
    __syncthreads();
    #pragma unroll
    for (int it = 0; it < 8; ++it) {
        int task = it * 64 + lane;
        int grp = task & 7, row = task >> 3;
        int n = n0 + wr * 64 + row;
        int jj = wc * 64 + grp * 8;
        int g2 = jj >> 5;
        int h0 = jj & 31;
        *(uint4*)&U2[(((size_t)(n * 2 + d) * 4 + g2) * 7776) + t * 32 + h0] =
            *(const uint4*)&Cw[row * 64 + grp * 8];
    }
}

// ---------------- mega tail (512 threads / 8 waves) ----------------
// LDS map (u16 offsets): Hs 0..19007 (264x72), ZT 19008 (64x248), FT 34880 (64x248),
//                        Rs 50752 (2x243x32), Xs 66304 (2x243x32). Total 81856 u16 = 163,712 B
#define HS0 0
#define ZT0 19008
#define FT0 34880
#define RS0 50752
#define XS0 66304
#define SH_U16 81856
__global__ __launch_bounds__(512) void k_tail(const u16* __restrict__ U2,
                                              const u16* __restrict__ Wrt,
                                              const u16* __restrict__ Wc,
                                              const float* __restrict__ v,
                                              const float* __restrict__ bbias,
                                              const float* __restrict__ bct,
                                              const float* __restrict__ x,
                                              float* __restrict__ out) {
    __shared__ __align__(16) u16 sh[SH_U16];
    u16* Hs = sh + HS0;
    u16* ZT = sh + ZT0;
    u16* FT = sh + FT0;
    u16* Rs = sh + RS0;
    u16* Xs = sh + XS0;
    const int tid = threadIdx.x;
    const int n = blockIdx.x;
    const int lane = tid & 63, w = tid >> 6;          // w in 0..7
    const int ml = lane & 15, q = lane >> 4;
    const u16* U2n = U2 + (size_t)n * 62208;

    for (int lay = 0; lay < 4; ++lay) {
        if (lay == 0) {
            // P1: DMA z planes -> Hs staging, f planes -> Xs staging (dead region)
            for (int d2 = 0; d2 < 2; ++d2) {
                dma_plane(U2n + (size_t)(d2 * 4 + 0) * 7776, Hs + d2 * 7776, w, lane);
                dma_plane(U2n + (size_t)(d2 * 4 + 1) * 7776, Xs + d2 * 7776, w, lane);
            }
            __syncthreads();
            // P2: blocked transpose z: Hs[d][t][h] -> ZT[(d*32+h)][t]  (b128 writes)
            //                        f: Xs[d][t][h] -> FT[(d*32+h)][t]
            for (int task = tid; task < 1984; task += 512) {
                int row = task & 63, tb = task >> 6;      // tb 0..30
                int dd = row >> 5, hh = row & 31;
                u16 tz[8], tf[8];
                #pragma unroll
                for (int k = 0; k < 8; ++k) {
                    int t = tb * 8 + k;
                    int ts = t < TnN ? t : (TnN - 1);      // clamp: t>=243 masked in chain
                    tz[k] = Hs[dd * 7776 + ts * 32 + hh];
                    tf[k] = Xs[dd * 7776 + ts * 32 + hh];
                }
                uint4 oz, of;
                oz.x = (unsigned)tz[0] | ((unsigned)tz[1] << 16);
                oz.y = (unsigned)tz[2] | ((unsigned)tz[3] << 16);
                oz.z = (unsigned)tz[4] | ((unsigned)tz[5] << 16);
                oz.w = (unsigned)tz[6] | ((unsigned)tz[7] << 16);
                of.x = (unsigned)tf[0] | ((unsigned)tf[1] << 16);
                of.y = (unsigned)tf[2] | ((unsigned)tf[3] << 16);
                of.z = (unsigned)tf[4] | ((unsigned)tf[5] << 16);
                of.w = (unsigned)tf[6] | ((unsigned)tf[7] << 16);
                *(uint4*)&ZT[row * 248 + tb * 8] = oz;
                *(uint4*)&FT[row * 248 + tb * 8] = of;
            }
            __syncthreads();
            // P3: issue r,x DMA now; the post-chain __syncthreads drains it,
            // so the ~62 KB transfer hides under the serial chain.
            for (int d2 = 0; d2 < 2; ++d2) {
                dma_plane(U2n + (size_t)(d2 * 4 + 2) * 7776, Rs + d2 * 7776, w, lane);
                dma_plane(U2n + (size_t)(d2 * 4 + 3) * 7776, Xs + d2 * 7776, w, lane);
            }
        } else {
            // recurrent GEMM, B direct from global (L2-hot, no intra-block reuse)
            const u16* Wl = Wrt + (size_t)(lay - 1) * 16384;
            f32x4 acc[2][16];
            #pragma unroll
            for (int mt = 0; mt < 2; ++mt)
                #pragma unroll
                for (int nt = 0; nt < 16; ++nt)
                    acc[mt][nt] = (f32x4){0.f, 0.f, 0.f, 0.f};
            #pragma unroll
            for (int c2 = 0; c2 < 2; ++c2) {
                int c0 = c2 * 32;
                bf16x8 af[2];
                #pragma unroll
                for (int mt = 0; mt < 2; ++mt)
                    af[mt] = *(const bf16x8*)&Hs[(w * 32 + mt * 16 + ml + 7) * 72 + c0 + q * 8];
                #pragma unroll
                for (int nt = 0; nt < 16; ++nt) {
                    bf16x8 bfr = *(const bf16x8*)&Wl[(size_t)(nt * 16 + ml) * 64 + c0 + q * 8];
                    #pragma unroll
                    for (int mt = 0; mt < 2; ++mt)
                        acc[mt][nt] = __builtin_amdgcn_mfma_f32_16x16x32_bf16(af[mt], bfr, acc[mt][nt], 0, 0, 0);
                }
            }
            // epilogue: same-thread acc, writes only regions dead since end-of-prev-layer barrier
            #pragma unroll
            for (int mt = 0; mt < 2; ++mt) {
                int t0 = w * 32 + mt * 16 + q * 4;
                if (t0 < TnN) {
                    bool vec = (t0 + 4 <= TnN);
                    #pragma unroll
                    for (int nt = 0; nt < 16; ++nt) {
                        int d2 = nt >> 3, g2 = (nt >> 1) & 3, hh = (nt & 1) * 16 + ml;
                        if (g2 < 2) {
                            u16* P = (g2 ? FT : ZT) + (d2 * 32 + hh) * 248;
                            if (vec) {
                                uint2 pv;
                                pv.x = (unsigned)f2bf(acc[mt][nt][0]) | ((unsigned)f2bf(acc[mt][nt][1]) << 16);
                                pv.y = (unsigned)f2bf(acc[mt][nt][2]) | ((unsigned)f2bf(acc[mt][nt][3]) << 16);
                                *(uint2*)&P[t0] = pv;
                            } else {
                                #pragma unroll
                                for (int r = 0; r < 4; ++r) {
                                    int t = t0 + r;
                                    if (t < TnN) P[t] = f2bf(acc[mt][nt][r]);
                                }
                            }
                        } else {
                            u16* P = (g2 == 2 ? Rs : Xs) + d2 * 7776 + hh;
                            #pragma unroll
                            for (int r = 0; r < 4; ++r) {
                                int t = t0 + r;
                                if (t < TnN) P[t * 32] = f2bf(acc[mt][nt][r]);
                            }
                        }
                    }
                }
            }
            __syncthreads();   // epilogue visible -> chain may read ZT/FT
        }
        if (lay == 0) __syncthreads();   // (lay0 path: transposes done above; keep barrier count aligned)

        const float* vv = v + (size_t)(lay * 2) * 64;
        const float* bv = bbias + (size_t)(lay * 2) * 64;

        // serial c-chains: wave0 d0 (forward), wave1 d1 (backward); direction compile-time
        if (w < 2 && lane < 32) {
            const int d = w, h = lane;
            const float vf = vv[d * 64 + h], bf_ = bv[d * 64 + h];
            const float kf = -LOG2E * vf;
            u16* Zr = &ZT[(d * 32 + h) * 248];
            u16* Fr = &FT[(d * 32 + h) * 248];
            if (d == 0) chain_run<0>(Zr, Fr, kf, bf_);
            else        chain_run<1>(Zr, Fr, kf, bf_);
        }
        __syncthreads();   // also drains the lay0 r/x DMA issued in P3

        // h-phase (parallel) + one-time guard zero
        if (lay == 0) {
            for (int i = tid; i < 21 * 72; i += 512) {
                int r = i / 72, ci = i - r * 72;
                int row = r < 7 ? r : (TnN + r);
                Hs[row * 72 + ci] = 0;
            }
        }
        for (int task = tid; task < 1984; task += 512) {
            int h = task & 31, d = (task >> 5) & 1, grp = task >> 6;
            int gb = grp * 8;
            const float vr_ = vv[d * 64 + 32 + h], br_ = bv[d * 64 + 32 + h];
            const float kr = -LOG2E * vr_;
            const u16* Cr = &ZT[(d * 32 + h) * 248];
            bf16x8 c8 = *(const bf16x8*)&Cr[gb];
            float cl[8];
            #pragma unroll
            for (int k = 0; k < 8; ++k) cl[k] = (float)c8[k];
            #pragma unroll
            for (int k = 0; k < 8; ++k) {
                int t = gb + k;
                if (t < TnN) {
                    float cpr;
                    if (d == 0) cpr = (t == 0) ? 0.f : (k ? cl[k - 1] : bf2f(Cr[gb - 1]));
                    else        cpr = (t == TnN - 1) ? 0.f : (k < 7 ? cl[k + 1] : bf2f(Cr[gb + 8]));
                    float ur = bf2f(Rs[d * 7776 + t * 32 + h]);
                    float ux = bf2f(Xs[d * 7776 + t * 32 + h]);
                    float xr = fmaf(kr, cpr, -LOG2E * (ur + br_));
                    float rg = __builtin_amdgcn_rcpf(1.f + hw_exp2(xr));
                    float hv = fmaf(rg, cl[k] - ux, ux);
                    Hs[(t + 7) * 72 + d * 32 + h] = f2bf(hv);
                }
            }
        }
        __syncthreads();
    }

    // ---- conv phase: A = Hs (stable), B direct from global -> barrier-free MFMA loop ----
    {
        const int b = n >> 7, f = n & 127;
        float* Cf = (float*)(sh + ZT0 + 3072);    // 250 x 68 fp32 in dead ZT/FT/Rs region
        f32x4 acc[2][4] = {};
        #pragma unroll 4
        for (int kc = 0; kc < 16; ++kc) {
            int kk = kc >> 1, ci0 = (kc & 1) * 32;
            bf16x8 af[2], bfv[4];
            #pragma unroll
            for (int nt = 0; nt < 4; ++nt)
                bfv[nt] = *(const bf16x8*)&Wc[(size_t)(nt * 16 + ml) * 512 + kc * 32 + q * 8];
            #pragma unroll
            for (int mt = 0; mt < 2; ++mt)
                af[mt] = *(const bf16x8*)&Hs[(w * 32 + mt * 16 + ml - kk + 7) * 72 + ci0 + q * 8];
            #pragma unroll
            for (int mt = 0; mt < 2; ++mt)
                #pragma unroll
                for (int nt = 0; nt < 4; ++nt)
                    acc[mt][nt] = __builtin_amdgcn_mfma_f32_16x16x32_bf16(af[mt], bfv[nt], acc[mt][nt], 0, 0, 0);
        }
        float bc[4];
        #pragma unroll
        for (int nt = 0; nt < 4; ++nt) bc[nt] = bct[nt * 16 + ml];
        #pragma unroll
        for (int mt = 0; mt < 2; ++mt)
            #pragma unroll
            for (int r = 0; r < 4; ++r) {
                int t = w * 32 + mt * 16 + q * 4 + r;
                if (t < Tt) {
                    #pragma unroll
                    for (int nt = 0; nt < 4; ++nt)
                        Cf[t * 68 + nt * 16 + ml] = acc[mt][nt][r] + bc[nt];
                }
            }
        __syncthreads();
        {
            const int sub = tid & 7;
            const int o = tid >> 3;               // 0..63, all channels in one pass
            const float* xrow = x + ((size_t)(b * 64 + o) * 128 + f) * Tt;
            float* orow = out + ((size_t)(b * 64 + o) * 128 + f) * Tt;
            #pragma unroll
            for (int it = 0; it < 16; ++it) {
                int j = it * 16 + sub * 2;
                if (j < Tt) {
                    float2 xv = *(const float2*)&xrow[j];
                    float2 ov;
                    ov.x = Cf[j * 68 + o] + xv.x;
                    ov.y = Cf[(j + 1) * 68 + o] + xv.y;
                    *(float2*)&orow[j] = ov;
                }
            }
        }
    }
}

extern "C" void kernel_launch(void* const* d_in, const int* in_sizes, int n_in,
                              void* d_out, int out_size, void* d_ws, size_t ws_size,
                              hipStream_t stream) {
    (void)in_sizes; (void)n_in; (void)out_size; (void)ws_size;
    const float* x     = (const float*)d_in[0];
    const float* gamma = (const float*)d_in[1];
    const float* beta  = (const float*)d_in[2];
    const float* W0    = (const float*)d_in[3];
    const float* Wr    = (const float*)d_in[4];
    const float* v     = (const float*)d_in[5];
    const float* bb    = (const float*)d_in[6];
    const float* wct   = (const float*)d_in[7];
    const float* bct   = (const float*)d_in[8];
    float* out = (float*)d_out;

    char* base = (char*)d_ws;
    float* stats = (float*)base;
    u16* W0t  = (u16*)(base + 256);                      // 262144 B
    u16* Wrt  = (u16*)(base + 256 + 262144);             // 98304 B
    u16* Wcto = (u16*)(base + 256 + 262144 + 98304);     // 65536 B
    char* base2 = base + 426240;
    u16* U2   = (u16*)base2;                             // 31.85 MB (live gemm0m->tail)
    char* base3 = base2 + 31850496;
    u16* Xb   = (u16*)base3;                             // 8.4 MB bf16 normalized (L2/L3-resident)

    hipMemsetAsync(stats, 0, 32, stream);
    k_stats<<<dim3(128, 2), 256, 0, stream>>>(x, stats);
    k_norm<<<(Nn * 64 * Tt + 255) / 256, 256, 0, stream>>>(x, stats, gamma, beta, Xb);
    k_packw<<<(212992 + 255) / 256, 256, 0, stream>>>(W0, Wr, wct, W0t, Wrt, Wcto);

    k_gemm0m<<<dim3(486, 2), 256, 0, stream>>>(Xb, W0t, U2);
    k_tail<<<dim3(256), 512, 0, stream>>>(U2, Wrt, Wcto, v, bb, bct, x, out);
}

// Round 3
// 274.048 us; speedup vs baseline: 1.1492x; 1.1492x over previous
//
#include <hip/hip_runtime.h>
#include <math.h>

#define Tt 250
#define TnN 243
#define Nn 256
#define EPS_ 1e-5f
#define LOG2E 1.44269504f

typedef unsigned short u16;
typedef __bf16 bf16x8 __attribute__((ext_vector_type(8)));
typedef float f32x4 __attribute__((ext_vector_type(4)));

__device__ __forceinline__ u16 f2bf(float f) {
    unsigned u = __builtin_bit_cast(unsigned, f);
    u += 0x7FFFu + ((u >> 16) & 1u);
    return (u16)(u >> 16);
}
__device__ __forceinline__ float bf2f(u16 s) {
    unsigned u = ((unsigned)s) << 16;
    return __builtin_bit_cast(float, u);
}
__device__ __forceinline__ float hw_exp2(float x) {
    return __builtin_amdgcn_exp2f(x);
}

__device__ __forceinline__ void async_load16(const void* g, void* l) {
    __builtin_amdgcn_global_load_lds(
        (const __attribute__((address_space(1))) unsigned int*)g,
        (__attribute__((address_space(3))) unsigned int*)l, 16, 0, 0);
}

// DMA one 15,552 B plane (243x32 u16) global->LDS, 8 waves cooperate
__device__ __forceinline__ void dma_plane(const u16* gsrc, u16* ldst, int w, int lane) {
    const char* g = (const char*)gsrc;
    char* l = (char*)ldst;
    for (int off = w * 1024; off < 15552; off += 8192) {
        int rem = 15552 - off;
        int lim = rem < 1024 ? rem : 1024;
        if (lane * 16 < lim) async_load16(g + off + lane * 16, l + off);
    }
}

// extract ushorts [S..S+7] from a 16-ushort window (two uint4), all static
template<int S>
__device__ __forceinline__ uint4 extract8(const uint4& a, const uint4& b) {
    const unsigned W[8] = {a.x, a.y, a.z, a.w, b.x, b.y, b.z, b.w};
    uint4 r;
    constexpr int i = S >> 1;
    if constexpr ((S & 1) == 0) {
        r.x = W[i]; r.y = W[i + 1]; r.z = W[i + 2]; r.w = W[i + 3];
    } else {
        r.x = (W[i] >> 16)     | (W[i + 1] << 16);
        r.y = (W[i + 1] >> 16) | (W[i + 2] << 16);
        r.z = (W[i + 2] >> 16) | (W[i + 3] << 16);
        r.w = (W[i + 3] >> 16) | (W[i + 4] << 16);
    }
    return r;
}

// serial c-chain over one transposed row pair, direction D compile-time:
// all vector extracts/inserts static -> registers only, no scratch.
template<int D>
__device__ __forceinline__ void chain_run(u16* Zr, u16* Fr, float kf, float bf_) {
    bf16x8 z8 = *(const bf16x8*)&Zr[D ? 240 : 0];
    bf16x8 f8 = *(const bf16x8*)&Fr[D ? 240 : 0];
    float c = 0.f;
    for (int grp = 0; grp < 31; ++grp) {
        int gb = D ? (30 - grp) * 8 : grp * 8;
        bf16x8 zn = z8, fn = f8;
        if (grp < 30) {
            int gbn = D ? (29 - grp) * 8 : (grp + 1) * 8;
            zn = *(const bf16x8*)&Zr[gbn];
            fn = *(const bf16x8*)&Fr[gbn];
        }
        bf16x8 co;
        #pragma unroll
        for (int k = 0; k < 8; ++k) {
            const int idx = D ? (7 - k) : k;     // constexpr after unroll
            int t = gb + idx;
            float uz = (float)z8[idx];
            float af = -LOG2E * ((float)f8[idx] + bf_);
            float xe = fmaf(kf, c, af);
            float fg = __builtin_amdgcn_rcpf(1.f + hw_exp2(xe));
            float cn = fmaf(fg, c - uz, uz);
            bool ok = (t < TnN);
            if (ok) c = cn;
            co[idx] = ok ? (__bf16)c : (__bf16)0.f;
        }
        *(bf16x8*)&Zr[gb] = co;
        z8 = zn; f8 = fn;
    }
}

// ---------------- stats ----------------
__global__ void k_stats(const float* __restrict__ x, float* __restrict__ stats) {
    int b = blockIdx.y;
    const float* xb = x + (size_t)b * 64 * 128 * Tt;
    const int n = 64 * 128 * Tt;
    float s = 0.f, s2 = 0.f;
    for (int i = blockIdx.x * blockDim.x + threadIdx.x; i < n; i += gridDim.x * blockDim.x) {
        float v = xb[i];
        s += v; s2 += v * v;
    }
    for (int off = 32; off; off >>= 1) {
        s  += __shfl_down(s, off);
        s2 += __shfl_down(s2, off);
    }
    __shared__ float ls[8], ls2[8];
    int lane = threadIdx.x & 63, w = threadIdx.x >> 6;
    if (lane == 0) { ls[w] = s; ls2[w] = s2; }
    __syncthreads();
    if (threadIdx.x == 0) {
        float a = 0.f, a2 = 0.f;
        int nw = blockDim.x >> 6;
        for (int i = 0; i < nw; i++) { a += ls[i]; a2 += ls2[i]; }
        atomicAdd(&stats[b * 2 + 0], a);
        atomicAdd(&stats[b * 2 + 1], a2);
    }
}

// ---------------- normalize -> bf16 [n][c][256] ----------------
__global__ void k_norm(const float* __restrict__ x, const float* __restrict__ stats,
                       const float* __restrict__ gamma, const float* __restrict__ beta,
                       u16* __restrict__ xu) {
    int idx = blockIdx.x * blockDim.x + threadIdx.x;
    const int total = Nn * 64 * Tt;
    if (idx >= total) return;
    int t = idx % Tt;
    int c = (idx / Tt) & 63;
    int n = idx / (Tt * 64);
    int b = n >> 7, f = n & 127;
    const float inv = 1.0f / (float)(64 * 128 * Tt);
    float mean = stats[b * 2 + 0] * inv;
    float var  = stats[b * 2 + 1] * inv - mean * mean;
    float rstd = rsqrtf(var + EPS_);
    float v = x[(((size_t)(b * 64 + c)) * 128 + f) * Tt + t];
    xu[((size_t)(n * 64 + c) << 8) + t] = f2bf((v - mean) * rstd * gamma[c] + beta[c]);
}

// ---------------- pack weights ----------------
__global__ void k_packw(const float* __restrict__ W0, const float* __restrict__ Wr,
                        const float* __restrict__ wct,
                        u16* __restrict__ W0t, u16* __restrict__ Wrt, u16* __restrict__ Wcto) {
    int idx = blockIdx.x * blockDim.x + threadIdx.x;
    if (idx < 131072) {
        int j = idx >> 9, p = idx & 511;
        W0t[idx] = f2bf(W0[(size_t)(j >> 7) * 65536 + p * 128 + (j & 127)]);
    } else if (idx < 180224) {
        int r = idx - 131072;
        int i = r & 63, j = (r >> 6) & 255, lidx = r >> 14;
        Wrt[r] = f2bf(Wr[(size_t)(lidx * 2 + (j >> 7)) * 8192 + i * 128 + (j & 127)]);
    } else if (idx < 212992) {
        int r = idx - 180224;
        int o = r >> 9; int k = r & 511; int kk = k >> 6, ci = k & 63;
        Wcto[r] = f2bf(wct[(size_t)ci * 512 + o * 8 + kk]);
    }
}

// ---------------- MFMA GEMM layer 0 (fused im2col, LDS-staged B) -> U2 [n][d][g][243][32] --
// A[m=(t,n)][c*8+k] = xu_bf[n][c][t+k], staged per-kc from the 8.4MB L2-resident tensor.
// B staged in LDS per-kc with coalesced reads (R1 pattern) -- B has full intra-block reuse.
__global__ __launch_bounds__(256) void k_gemm0m(const u16* __restrict__ Xb,
                                                const u16* __restrict__ B,
                                                u16* __restrict__ U2) {
    __shared__ u16 sh[16384];
    u16* As = sh;
    u16* Bs = sh + 5120;
    const int tid = threadIdx.x;
    const int t = blockIdx.x >> 1;
    const int n0 = (blockIdx.x & 1) * 128;
    const int j0 = blockIdx.y * 128;
    const int d = blockIdx.y;
    const int lane = tid & 63, w = tid >> 6;
    const int wr = w >> 1, wc = w & 1;
    const int ml = lane & 15, q = lane >> 4;
    const int ta = t & ~7, shv = t & 7;     // block-uniform shift
    f32x4 acc[4][4] = {};
    for (int kc = 0; kc < 16; ++kc) {
        int c0 = kc * 32;
        #pragma unroll
        for (int i = 0; i < 2; ++i) {
            int task = tid + i * 256;
            int row = task >> 2, cl = task & 3;
            // B: coalesced 16B per lane from W0t (L2-hot)
            *(uint4*)&Bs[row * 40 + cl * 8] = *(const uint4*)&B[(size_t)(j0 + row) * 512 + c0 + cl * 8];
            // A: windowed extract from Xb (im2col on the fly)
            const u16* src = &Xb[((size_t)((n0 + row) * 64 + kc * 4 + cl) << 8) + ta];
            uint4 L0 = *(const uint4*)src;
            uint4 L1 = *(const uint4*)(src + 8);
            uint4 ov;
            switch (shv) {
                case 0:  ov = extract8<0>(L0, L1); break;
                case 1:  ov = extract8<1>(L0, L1); break;
                case 2:  ov = extract8<2>(L0, L1); break;
                case 3:  ov = extract8<3>(L0, L1); break;
                case 4:  ov = extract8<4>(L0, L1); break;
                case 5:  ov = extract8<5>(L0, L1); break;
                case 6:  ov = extract8<6>(L0, L1); break;
                default: ov = extract8<7>(L0, L1); break;
            }
            *(uint4*)&As[row * 40 + cl * 8] = ov;
        }
        __syncthreads();
        bf16x8 af[4], bfv[4];
        #pragma unroll
        for (int mt = 0; mt < 4; ++mt) af[mt] = *(const bf16x8*)&As[(wr * 64 + mt * 16 + ml) * 40 + q * 8];
        #pragma unroll
        for (int nt = 0; nt < 4; ++nt) bfv[nt] = *(const bf16x8*)&Bs[(wc * 64 + nt * 16 + ml) * 40 + q * 8];
        #pragma unroll
        for (int mt = 0; mt < 4; ++mt)
            #pragma unroll
            for (int nt = 0; nt < 4; ++nt)
                acc[mt][nt] = __builtin_amdgcn_mfma_f32_16x16x32_bf16(af[mt], bfv[nt], acc[mt][nt], 0, 0, 0);
        __syncthreads();
    }
    u16* Cw = sh + w * 4096;
    #pragma unroll
    for (int mt = 0; mt < 4; ++mt)
        #pragma unroll
        for (int nt = 0; nt < 4; ++nt)
            #pragma unroll
            for (int r = 0; r < 4; ++r)
                Cw[(mt * 16 + q * 4 + r) * 64 + nt * 16 + ml] = f2bf(acc[mt][nt][r]);
    __syncthreads();
    #pragma unroll
    for (int it = 0; it < 8; ++it) {
        int task = it * 64 + lane;
        int grp = task & 7, row = task >> 3;
        int n = n0 + wr * 64 + row;
        int jj = wc * 64 + grp * 8;
        int g2 = jj >> 5;
        int h0 = jj & 31;
        *(uint4*)&U2[(((size_t)(n * 2 + d) * 4 + g2) * 7776) + t * 32 + h0] =
            *(const uint4*)&Cw[row * 64 + grp * 8];
    }
}

// ---------------- mega tail (512 threads / 8 waves) ----------------
// LDS map (u16 offsets): Hs 0..19007 (264x72), ZT 19008 (64x248), FT 34880 (64x248),
//                        Rs 50752 (2x243x32), Xs 66304 (2x243x32). Total 81856 u16 = 163,712 B
#define HS0 0
#define ZT0 19008
#define FT0 34880
#define RS0 50752
#define XS0 66304
#define SH_U16 81856
__global__ __launch_bounds__(512) void k_tail(const u16* __restrict__ U2,
                                              const u16* __restrict__ Wrt,
                                              const u16* __restrict__ Wc,
                                              const float* __restrict__ v,
                                              const float* __restrict__ bbias,
                                              const float* __restrict__ bct,
                                              const float* __restrict__ x,
                                              float* __restrict__ out) {
    __shared__ __align__(16) u16 sh[SH_U16];
    u16* Hs = sh + HS0;
    u16* ZT = sh + ZT0;
    u16* FT = sh + FT0;
    u16* Rs = sh + RS0;
    u16* Xs = sh + XS0;
    const int tid = threadIdx.x;
    const int n = blockIdx.x;
    const int lane = tid & 63, w = tid >> 6;          // w in 0..7
    const int ml = lane & 15, q = lane >> 4;
    const u16* U2n = U2 + (size_t)n * 62208;

    for (int lay = 0; lay < 4; ++lay) {
        if (lay == 0) {
            // P1: DMA z planes -> Hs staging, f planes -> Xs staging (dead region)
            for (int d2 = 0; d2 < 2; ++d2) {
                dma_plane(U2n + (size_t)(d2 * 4 + 0) * 7776, Hs + d2 * 7776, w, lane);
                dma_plane(U2n + (size_t)(d2 * 4 + 1) * 7776, Xs + d2 * 7776, w, lane);
            }
            __syncthreads();
            // P2: blocked transpose z: Hs[d][t][h] -> ZT[(d*32+h)][t]  (b128 writes)
            //                        f: Xs[d][t][h] -> FT[(d*32+h)][t]
            for (int task = tid; task < 1984; task += 512) {
                int row = task & 63, tb = task >> 6;      // tb 0..30
                int dd = row >> 5, hh = row & 31;
                u16 tz[8], tf[8];
                #pragma unroll
                for (int k = 0; k < 8; ++k) {
                    int t = tb * 8 + k;
                    int ts = t < TnN ? t : (TnN - 1);      // clamp: t>=243 masked in chain
                    tz[k] = Hs[dd * 7776 + ts * 32 + hh];
                    tf[k] = Xs[dd * 7776 + ts * 32 + hh];
                }
                uint4 oz, of;
                oz.x = (unsigned)tz[0] | ((unsigned)tz[1] << 16);
                oz.y = (unsigned)tz[2] | ((unsigned)tz[3] << 16);
                oz.z = (unsigned)tz[4] | ((unsigned)tz[5] << 16);
                oz.w = (unsigned)tz[6] | ((unsigned)tz[7] << 16);
                of.x = (unsigned)tf[0] | ((unsigned)tf[1] << 16);
                of.y = (unsigned)tf[2] | ((unsigned)tf[3] << 16);
                of.z = (unsigned)tf[4] | ((unsigned)tf[5] << 16);
                of.w = (unsigned)tf[6] | ((unsigned)tf[7] << 16);
                *(uint4*)&ZT[row * 248 + tb * 8] = oz;
                *(uint4*)&FT[row * 248 + tb * 8] = of;
            }
            __syncthreads();
            // P3: issue r,x DMA now; the post-chain __syncthreads drains it,
            // so the ~62 KB transfer hides under the serial chain.
            for (int d2 = 0; d2 < 2; ++d2) {
                dma_plane(U2n + (size_t)(d2 * 4 + 2) * 7776, Rs + d2 * 7776, w, lane);
                dma_plane(U2n + (size_t)(d2 * 4 + 3) * 7776, Xs + d2 * 7776, w, lane);
            }
        } else {
            // B staging in (dead) ZT region
            u16* Bst = sh + ZT0;     // 256 x 72
            const u16* Wl = Wrt + (size_t)(lay - 1) * 16384;
            #pragma unroll
            for (int it = 0; it < 4; ++it) {
                int task = it * 512 + tid;
                int j = task >> 3, grp = task & 7;
                *(uint4*)&Bst[j * 72 + grp * 8] = *(const uint4*)&Wl[j * 64 + grp * 8];
            }
            __syncthreads();
            f32x4 acc[2][16];
            #pragma unroll
            for (int mt = 0; mt < 2; ++mt)
                #pragma unroll
                for (int nt = 0; nt < 16; ++nt)
                    acc[mt][nt] = (f32x4){0.f, 0.f, 0.f, 0.f};
            #pragma unroll
            for (int c2 = 0; c2 < 2; ++c2) {
                int c0 = c2 * 32;
                bf16x8 af[2];
                #pragma unroll
                for (int mt = 0; mt < 2; ++mt)
                    af[mt] = *(const bf16x8*)&Hs[(w * 32 + mt * 16 + ml + 7) * 72 + c0 + q * 8];
                #pragma unroll
                for (int nt = 0; nt < 16; ++nt) {
                    bf16x8 bfr = *(const bf16x8*)&Bst[(nt * 16 + ml) * 72 + c0 + q * 8];
                    #pragma unroll
                    for (int mt = 0; mt < 2; ++mt)
                        acc[mt][nt] = __builtin_amdgcn_mfma_f32_16x16x32_bf16(af[mt], bfr, acc[mt][nt], 0, 0, 0);
                }
            }
            __syncthreads();   // all B reads done -> ZT/FT writable
            #pragma unroll
            for (int mt = 0; mt < 2; ++mt) {
                int t0 = w * 32 + mt * 16 + q * 4;
                if (t0 < TnN) {
                    bool vec = (t0 + 4 <= TnN);
                    #pragma unroll
                    for (int nt = 0; nt < 16; ++nt) {
                        int d2 = nt >> 3, g2 = (nt >> 1) & 3, hh = (nt & 1) * 16 + ml;
                        if (g2 < 2) {
                            u16* P = (g2 ? FT : ZT) + (d2 * 32 + hh) * 248;
                            if (vec) {
                                uint2 pv;
                                pv.x = (unsigned)f2bf(acc[mt][nt][0]) | ((unsigned)f2bf(acc[mt][nt][1]) << 16);
                                pv.y = (unsigned)f2bf(acc[mt][nt][2]) | ((unsigned)f2bf(acc[mt][nt][3]) << 16);
                                *(uint2*)&P[t0] = pv;
                            } else {
                                #pragma unroll
                                for (int r = 0; r < 4; ++r) {
                                    int t = t0 + r;
                                    if (t < TnN) P[t] = f2bf(acc[mt][nt][r]);
                                }
                            }
                        } else {
                            u16* P = (g2 == 2 ? Rs : Xs) + d2 * 7776 + hh;
                            #pragma unroll
                            for (int r = 0; r < 4; ++r) {
                                int t = t0 + r;
                                if (t < TnN) P[t * 32] = f2bf(acc[mt][nt][r]);
                            }
                        }
                    }
                }
            }
            __syncthreads();
        }

        const float* vv = v + (size_t)(lay * 2) * 64;
        const float* bv = bbias + (size_t)(lay * 2) * 64;

        // serial c-chains: wave0 d0 (forward), wave1 d1 (backward); direction compile-time
        if (w < 2 && lane < 32) {
            const int d = w, h = lane;
            const float vf = vv[d * 64 + h], bf_ = bv[d * 64 + h];
            const float kf = -LOG2E * vf;
            u16* Zr = &ZT[(d * 32 + h) * 248];
            u16* Fr = &FT[(d * 32 + h) * 248];
            if (d == 0) chain_run<0>(Zr, Fr, kf, bf_);
            else        chain_run<1>(Zr, Fr, kf, bf_);
        }
        __syncthreads();   // also drains the lay0 r/x DMA issued in P3

        // h-phase (parallel) + one-time guard zero
        if (lay == 0) {
            for (int i = tid; i < 21 * 72; i += 512) {
                int r = i / 72, ci = i - r * 72;
                int row = r < 7 ? r : (TnN + r);
                Hs[row * 72 + ci] = 0;
            }
        }
        for (int task = tid; task < 1984; task += 512) {
            int h = task & 31, d = (task >> 5) & 1, grp = task >> 6;
            int gb = grp * 8;
            const float vr_ = vv[d * 64 + 32 + h], br_ = bv[d * 64 + 32 + h];
            const float kr = -LOG2E * vr_;
            const u16* Cr = &ZT[(d * 32 + h) * 248];
            bf16x8 c8 = *(const bf16x8*)&Cr[gb];
            float cl[8];
            #pragma unroll
            for (int k = 0; k < 8; ++k) cl[k] = (float)c8[k];
            #pragma unroll
            for (int k = 0; k < 8; ++k) {
                int t = gb + k;
                if (t < TnN) {
                    float cpr;
                    if (d == 0) cpr = (t == 0) ? 0.f : (k ? cl[k - 1] : bf2f(Cr[gb - 1]));
                    else        cpr = (t == TnN - 1) ? 0.f : (k < 7 ? cl[k + 1] : bf2f(Cr[gb + 8]));
                    float ur = bf2f(Rs[d * 7776 + t * 32 + h]);
                    float ux = bf2f(Xs[d * 7776 + t * 32 + h]);
                    float xr = fmaf(kr, cpr, -LOG2E * (ur + br_));
                    float rg = __builtin_amdgcn_rcpf(1.f + hw_exp2(xr));
                    float hv = fmaf(rg, cl[k] - ux, ux);
                    Hs[(t + 7) * 72 + d * 32 + h] = f2bf(hv);
                }
            }
        }
        __syncthreads();
    }

    // ---- conv phase: A = Hs, scratch in dead ZT+ region ----
    {
        const int b = n >> 7, f = n & 127;
        u16* Bs = sh + ZT0;                       // 64 x 40
        float* Cf = (float*)(sh + ZT0 + 3072);    // 250 x 68 fp32
        f32x4 acc[2][4] = {};
        for (int kc = 0; kc < 16; ++kc) {
            int kk = kc >> 1, ci0 = (kc & 1) * 32;
            if (tid < 256) {
                int o = tid >> 2, grp = tid & 3;
                *(uint4*)&Bs[o * 40 + grp * 8] = *(const uint4*)&Wc[(size_t)o * 512 + kc * 32 + grp * 8];
            }
            __syncthreads();
            bf16x8 af[2], bfv[4];
            #pragma unroll
            for (int mt = 0; mt < 2; ++mt)
                af[mt] = *(const bf16x8*)&Hs[(w * 32 + mt * 16 + ml - kk + 7) * 72 + ci0 + q * 8];
            #pragma unroll
            for (int nt = 0; nt < 4; ++nt)
                bfv[nt] = *(const bf16x8*)&Bs[(nt * 16 + ml) * 40 + q * 8];
            #pragma unroll
            for (int mt = 0; mt < 2; ++mt)
                #pragma unroll
                for (int nt = 0; nt < 4; ++nt)
                    acc[mt][nt] = __builtin_amdgcn_mfma_f32_16x16x32_bf16(af[mt], bfv[nt], acc[mt][nt], 0, 0, 0);
            __syncthreads();
        }
        float bc[4];
        #pragma unroll
        for (int nt = 0; nt < 4; ++nt) bc[nt] = bct[nt * 16 + ml];
        #pragma unroll
        for (int mt = 0; mt < 2; ++mt)
            #pragma unroll
            for (int r = 0; r < 4; ++r) {
                int t = w * 32 + mt * 16 + q * 4 + r;
                if (t < Tt) {
                    #pragma unroll
                    for (int nt = 0; nt < 4; ++nt)
                        Cf[t * 68 + nt * 16 + ml] = acc[mt][nt][r] + bc[nt];
                }
            }
        __syncthreads();
        {
            const int sub = tid & 7;
            const int o = tid >> 3;               // 0..63, all channels in one pass
            const float* xrow = x + ((size_t)(b * 64 + o) * 128 + f) * Tt;
            float* orow = out + ((size_t)(b * 64 + o) * 128 + f) * Tt;
            #pragma unroll
            for (int it = 0; it < 16; ++it) {
                int j = it * 16 + sub * 2;
                if (j < Tt) {
                    float2 xv = *(const float2*)&xrow[j];
                    float2 ov;
                    ov.x = Cf[j * 68 + o] + xv.x;
                    ov.y = Cf[(j + 1) * 68 + o] + xv.y;
                    *(float2*)&orow[j] = ov;
                }
            }
        }
    }
}

extern "C" void kernel_launch(void* const* d_in, const int* in_sizes, int n_in,
                              void* d_out, int out_size, void* d_ws, size_t ws_size,
                              hipStream_t stream) {
    (void)in_sizes; (void)n_in; (void)out_size; (void)ws_size;
    const float* x     = (const float*)d_in[0];
    const float* gamma = (const float*)d_in[1];
    const float* beta  = (const float*)d_in[2];
    const float* W0    = (const float*)d_in[3];
    const float* Wr    = (const float*)d_in[4];
    const float* v     = (const float*)d_in[5];
    const float* bb    = (const float*)d_in[6];
    const float* wct   = (const float*)d_in[7];
    const float* bct   = (const float*)d_in[8];
    float* out = (float*)d_out;

    char* base = (char*)d_ws;
    float* stats = (float*)base;
    u16* W0t  = (u16*)(base + 256);                      // 262144 B
    u16* Wrt  = (u16*)(base + 256 + 262144);             // 98304 B
    u16* Wcto = (u16*)(base + 256 + 262144 + 98304);     // 65536 B
    char* base2 = base + 426240;
    u16* U2   = (u16*)base2;                             // 31.85 MB (live gemm0m->tail)
    char* base3 = base2 + 31850496;
    u16* Xb   = (u16*)base3;                             // 8.4 MB bf16 normalized (L2/L3-resident)

    hipMemsetAsync(stats, 0, 32, stream);
    k_stats<<<dim3(128, 2), 256, 0, stream>>>(x, stats);
    k_norm<<<(Nn * 64 * Tt + 255) / 256, 256, 0, stream>>>(x, stats, gamma, beta, Xb);
    k_packw<<<(212992 + 255) / 256, 256, 0, stream>>>(W0, Wr, wct, W0t, Wrt, Wcto);

    k_gemm0m<<<dim3(486, 2), 256, 0, stream>>>(Xb, W0t, U2);
    k_tail<<<dim3(256), 512, 0, stream>>>(U2, Wrt, Wcto, v, bb, bct, x, out);
}

// Round 4
// 231.617 us; speedup vs baseline: 1.3598x; 1.1832x over previous
//
#include <hip/hip_runtime.h>
#include <math.h>

#define Tt 250
#define TnN 243
#define Nn 256
#define EPS_ 1e-5f
#define LOG2E 1.44269504f

typedef unsigned short u16;
typedef __bf16 bf16x8 __attribute__((ext_vector_type(8)));
typedef float f32x4 __attribute__((ext_vector_type(4)));

__device__ __forceinline__ u16 f2bf(float f) {
    unsigned u = __builtin_bit_cast(unsigned, f);
    u += 0x7FFFu + ((u >> 16) & 1u);
    return (u16)(u >> 16);
}
__device__ __forceinline__ float bf2f(u16 s) {
    unsigned u = ((unsigned)s) << 16;
    return __builtin_bit_cast(float, u);
}
__device__ __forceinline__ float hw_exp2(float x) {
    return __builtin_amdgcn_exp2f(x);
}

// serial c-chain over one transposed row pair, direction D compile-time:
// all vector extracts/inserts static -> registers only, no scratch.
template<int D>
__device__ __forceinline__ void chain_run(u16* Zr, u16* Fr, float kf, float bf_) {
    bf16x8 z8 = *(const bf16x8*)&Zr[D ? 240 : 0];
    bf16x8 f8 = *(const bf16x8*)&Fr[D ? 240 : 0];
    float c = 0.f;
    for (int grp = 0; grp < 31; ++grp) {
        int gb = D ? (30 - grp) * 8 : grp * 8;
        bf16x8 zn = z8, fn = f8;
        if (grp < 30) {
            int gbn = D ? (29 - grp) * 8 : (grp + 1) * 8;
            zn = *(const bf16x8*)&Zr[gbn];
            fn = *(const bf16x8*)&Fr[gbn];
        }
        bf16x8 co;
        #pragma unroll
        for (int k = 0; k < 8; ++k) {
            const int idx = D ? (7 - k) : k;     // constexpr after unroll
            int t = gb + idx;
            float uz = (float)z8[idx];
            float af = -LOG2E * ((float)f8[idx] + bf_);
            float xe = fmaf(kf, c, af);
            float fg = __builtin_amdgcn_rcpf(1.f + hw_exp2(xe));
            float cn = fmaf(fg, c - uz, uz);
            bool ok = (t < TnN);
            if (ok) c = cn;
            co[idx] = ok ? (__bf16)c : (__bf16)0.f;
        }
        *(bf16x8*)&Zr[gb] = co;
        z8 = zn; f8 = fn;
    }
}

// ---------------- stats ----------------
__global__ void k_stats(const float* __restrict__ x, float* __restrict__ stats) {
    int b = blockIdx.y;
    const float* xb = x + (size_t)b * 64 * 128 * Tt;
    const int n = 64 * 128 * Tt;
    float s = 0.f, s2 = 0.f;
    for (int i = blockIdx.x * blockDim.x + threadIdx.x; i < n; i += gridDim.x * blockDim.x) {
        float v = xb[i];
        s += v; s2 += v * v;
    }
    for (int off = 32; off; off >>= 1) {
        s  += __shfl_down(s, off);
        s2 += __shfl_down(s2, off);
    }
    __shared__ float ls[8], ls2[8];
    int lane = threadIdx.x & 63, w = threadIdx.x >> 6;
    if (lane == 0) { ls[w] = s; ls2[w] = s2; }
    __syncthreads();
    if (threadIdx.x == 0) {
        float a = 0.f, a2 = 0.f;
        int nw = blockDim.x >> 6;
        for (int i = 0; i < nw; i++) { a += ls[i]; a2 += ls2[i]; }
        atomicAdd(&stats[b * 2 + 0], a);
        atomicAdd(&stats[b * 2 + 1], a2);
    }
}

// ---------------- normalize + transpose -> bf16 XbT[n][256 t][64 c] ----------------
__global__ __launch_bounds__(256) void k_norm(const float* __restrict__ x, const float* __restrict__ stats,
                       const float* __restrict__ gamma, const float* __restrict__ beta,
                       u16* __restrict__ xbt) {
    __shared__ u16 lt[64 * 260];
    const int n = blockIdx.x, tid = threadIdx.x;
    const int b = n >> 7, f = n & 127;
    const float inv = 1.0f / (float)(64 * 128 * Tt);
    float mean = stats[b * 2 + 0] * inv;
    float var  = stats[b * 2 + 1] * inv - mean * mean;
    float rstd = rsqrtf(var + EPS_);
    const int c = tid >> 2, vq = tid & 3;
    const float gm = gamma[c] * rstd;
    const float bt = beta[c] - mean * gm;
    const float* xr = x + ((size_t)(b * 64 + c) * 128 + f) * Tt;
    #pragma unroll
    for (int j = 0; j < 32; ++j) {
        int t0 = vq * 2 + j * 8;         // even t, covers 0..254
        unsigned pv = 0u;
        if (t0 < Tt) {                    // t0 <= 248: float2 in-bounds
            float2 xv = *(const float2*)&xr[t0];
            pv = (unsigned)f2bf(fmaf(xv.x, gm, bt)) | ((unsigned)f2bf(fmaf(xv.y, gm, bt)) << 16);
        }
        *(unsigned*)&lt[c * 260 + t0] = pv;   // zeros for t >= 250
    }
    __syncthreads();
    const int cg = tid & 7, tq = tid >> 3;
    for (int it = 0; it < 8; ++it) {
        int t = it * 32 + tq;
        u16 tmp[8];
        #pragma unroll
        for (int jj = 0; jj < 8; ++jj) tmp[jj] = lt[(cg * 8 + jj) * 260 + t];
        uint4 o;
        o.x = (unsigned)tmp[0] | ((unsigned)tmp[1] << 16);
        o.y = (unsigned)tmp[2] | ((unsigned)tmp[3] << 16);
        o.z = (unsigned)tmp[4] | ((unsigned)tmp[5] << 16);
        o.w = (unsigned)tmp[6] | ((unsigned)tmp[7] << 16);
        *(uint4*)&xbt[(size_t)n * 16384 + t * 64 + cg * 8] = o;
    }
}

// ---------------- pack weights ----------------
// W0k[k][j][c] = W0[d = j>>7][c*8+k][j&127]   (j = d*128 + g*32 + h, 0..255)
__global__ void k_packw(const float* __restrict__ W0, const float* __restrict__ Wr,
                        const float* __restrict__ wct,
                        u16* __restrict__ W0k, u16* __restrict__ Wrt, u16* __restrict__ Wcto) {
    int idx = blockIdx.x * blockDim.x + threadIdx.x;
    if (idx < 131072) {
        int k = idx >> 14, j = (idx >> 6) & 255, c = idx & 63;
        int d = j >> 7, ck = c * 8 + k;
        W0k[idx] = f2bf(W0[((size_t)d * 512 + ck) * 128 + (j & 127)]);
    } else if (idx < 180224) {
        int r = idx - 131072;
        int i = r & 63, j = (r >> 6) & 255, lidx = r >> 14;
        Wrt[r] = f2bf(Wr[(size_t)(lidx * 2 + (j >> 7)) * 8192 + i * 128 + (j & 127)]);
    } else if (idx < 212992) {
        int r = idx - 180224;
        int o = r >> 9; int k = r & 511; int kk = k >> 6, ci = k & 63;
        Wcto[r] = f2bf(wct[(size_t)ci * 512 + o * 8 + kk]);
    }
}

// shared GEMM epilogue: acc[2][16] -> ZT/FT (transposed [h][t]) and Rs/Xs ([t][h] planes)
__device__ __forceinline__ void epi16(f32x4 (&acc)[2][16], u16* ZT, u16* FT, u16* Rs, u16* Xs,
                                      int w, int ml, int q) {
    #pragma unroll
    for (int mt = 0; mt < 2; ++mt) {
        int t0 = w * 32 + mt * 16 + q * 4;
        if (t0 < TnN) {
            bool vec = (t0 + 4 <= TnN);
            #pragma unroll
            for (int nt = 0; nt < 16; ++nt) {
                int d2 = nt >> 3, g2 = (nt >> 1) & 3, hh = (nt & 1) * 16 + ml;
                if (g2 < 2) {
                    u16* P = (g2 ? FT : ZT) + (d2 * 32 + hh) * 248;
                    if (vec) {
                        uint2 pv;
                        pv.x = (unsigned)f2bf(acc[mt][nt][0]) | ((unsigned)f2bf(acc[mt][nt][1]) << 16);
                        pv.y = (unsigned)f2bf(acc[mt][nt][2]) | ((unsigned)f2bf(acc[mt][nt][3]) << 16);
                        *(uint2*)&P[t0] = pv;
                    } else {
                        #pragma unroll
                        for (int r = 0; r < 4; ++r) {
                            int t = t0 + r;
                            if (t < TnN) P[t] = f2bf(acc[mt][nt][r]);
                        }
                    }
                } else {
                    u16* P = (g2 == 2 ? Rs : Xs) + d2 * 7776 + hh;
                    #pragma unroll
                    for (int r = 0; r < 4; ++r) {
                        int t = t0 + r;
                        if (t < TnN) P[t * 32] = f2bf(acc[mt][nt][r]);
                    }
                }
            }
        }
    }
}

// ---------------- mega tail (512 threads / 8 waves) ----------------
// LDS map (u16 offsets): Hs 0..19007 (264x72), ZT 19008 (64x248), FT 34880 (64x248),
//                        Rs 50752 (2x243x32), Xs 66304 (2x243x32). Total 81856 u16 = 163,712 B
// During layer-0 GEMM: Hs holds XbT tile [256+pad][72]; B double-buffers live at ZT0 /
// ZT0+18432 (spanning dead ZT/FT/Rs); all outputs written by epi16 after the k-loop.
#define HS0 0
#define ZT0 19008
#define FT0 34880
#define RS0 50752
#define XS0 66304
#define SH_U16 81856
__global__ __launch_bounds__(512) void k_tail(const u16* __restrict__ XbT,
                                              const u16* __restrict__ W0k,
                                              const u16* __restrict__ Wrt,
                                              const u16* __restrict__ Wc,
                                              const float* __restrict__ v,
                                              const float* __restrict__ bbias,
                                              const float* __restrict__ bct,
                                              const float* __restrict__ x,
                                              float* __restrict__ out) {
    __shared__ __align__(16) u16 sh[SH_U16];
    u16* Hs = sh + HS0;
    u16* ZT = sh + ZT0;
    u16* FT = sh + FT0;
    u16* Rs = sh + RS0;
    u16* Xs = sh + XS0;
    const int tid = threadIdx.x;
    const int n = blockIdx.x;
    const int lane = tid & 63, w = tid >> 6;          // w in 0..7
    const int ml = lane & 15, q = lane >> 4;

    for (int lay = 0; lay < 4; ++lay) {
        if (lay == 0) {
            // ---- fused layer-0 GEMM: acc[t][j] = sum_k sum_c XbT[n][t+k][c] * W0k[k][j][c]
            const u16* Xn = XbT + (size_t)n * 16384;
            #pragma unroll
            for (int it = 0; it < 4; ++it) {            // stage A tile: [t 0..255][c 0..63] -> [t][72]
                int task = it * 512 + tid;
                *(uint4*)&Hs[(task >> 3) * 72 + (task & 7) * 8] = *(const uint4*)&Xn[task * 8];
            }
            u16* Bb0 = sh + ZT0;                        // 256 x 72 u16 each, dbuf
            u16* Bb1 = sh + ZT0 + 18432;
            #pragma unroll
            for (int it = 0; it < 4; ++it) {            // stage B k=0
                int task = it * 512 + tid;
                *(uint4*)&Bb0[(task >> 3) * 72 + (task & 7) * 8] = *(const uint4*)&W0k[task * 8];
            }
            __syncthreads();
            f32x4 acc[2][16];
            #pragma unroll
            for (int mt = 0; mt < 2; ++mt)
                #pragma unroll
                for (int nt = 0; nt < 16; ++nt)
                    acc[mt][nt] = (f32x4){0.f, 0.f, 0.f, 0.f};
            for (int k = 0; k < 8; ++k) {
                u16* Bl = (k & 1) ? Bb1 : Bb0;
                if (k < 7) {                             // prefetch k+1 into the other buffer
                    const u16* Bg = W0k + (size_t)(k + 1) * 16384;
                    u16* Bw = (k & 1) ? Bb0 : Bb1;
                    uint4 pb[4];
                    #pragma unroll
                    for (int it = 0; it < 4; ++it) pb[it] = *(const uint4*)&Bg[(it * 512 + tid) * 8];
                    #pragma unroll
                    for (int it = 0; it < 4; ++it) {
                        int task = it * 512 + tid;
                        *(uint4*)&Bw[(task >> 3) * 72 + (task & 7) * 8] = pb[it];
                    }
                }
                #pragma unroll
                for (int c2 = 0; c2 < 2; ++c2) {
                    int c0 = c2 * 32;
                    bf16x8 af[2];
                    #pragma unroll
                    for (int mt = 0; mt < 2; ++mt)
                        af[mt] = *(const bf16x8*)&Hs[(w * 32 + mt * 16 + ml + k) * 72 + c0 + q * 8];
                    #pragma unroll
                    for (int nt = 0; nt < 16; ++nt) {
                        bf16x8 bfr = *(const bf16x8*)&Bl[(nt * 16 + ml) * 72 + c0 + q * 8];
                        #pragma unroll
                        for (int mt = 0; mt < 2; ++mt)
                            acc[mt][nt] = __builtin_amdgcn_mfma_f32_16x16x32_bf16(af[mt], bfr, acc[mt][nt], 0, 0, 0);
                    }
                }
                __syncthreads();
            }
            epi16(acc, ZT, FT, Rs, Xs, w, ml, q);
            __syncthreads();
        } else {
            // B staging in (dead) ZT region
            u16* Bst = sh + ZT0;     // 256 x 72
            const u16* Wl = Wrt + (size_t)(lay - 1) * 16384;
            #pragma unroll
            for (int it = 0; it < 4; ++it) {
                int task = it * 512 + tid;
                int j = task >> 3, grp = task & 7;
                *(uint4*)&Bst[j * 72 + grp * 8] = *(const uint4*)&Wl[j * 64 + grp * 8];
            }
            __syncthreads();
            f32x4 acc[2][16];
            #pragma unroll
            for (int mt = 0; mt < 2; ++mt)
                #pragma unroll
                for (int nt = 0; nt < 16; ++nt)
                    acc[mt][nt] = (f32x4){0.f, 0.f, 0.f, 0.f};
            #pragma unroll
            for (int c2 = 0; c2 < 2; ++c2) {
                int c0 = c2 * 32;
                bf16x8 af[2];
                #pragma unroll
                for (int mt = 0; mt < 2; ++mt)
                    af[mt] = *(const bf16x8*)&Hs[(w * 32 + mt * 16 + ml + 7) * 72 + c0 + q * 8];
                #pragma unroll
                for (int nt = 0; nt < 16; ++nt) {
                    bf16x8 bfr = *(const bf16x8*)&Bst[(nt * 16 + ml) * 72 + c0 + q * 8];
                    #pragma unroll
                    for (int mt = 0; mt < 2; ++mt)
                        acc[mt][nt] = __builtin_amdgcn_mfma_f32_16x16x32_bf16(af[mt], bfr, acc[mt][nt], 0, 0, 0);
                }
            }
            __syncthreads();   // all B reads done -> ZT/FT writable
            epi16(acc, ZT, FT, Rs, Xs, w, ml, q);
            __syncthreads();
        }

        const float* vv = v + (size_t)(lay * 2) * 64;
        const float* bv = bbias + (size_t)(lay * 2) * 64;

        // serial c-chains: wave0 d0 (forward), wave1 d1 (backward); direction compile-time
        if (w < 2 && lane < 32) {
            const int d = w, h = lane;
            const float vf = vv[d * 64 + h], bf_ = bv[d * 64 + h];
            const float kf = -LOG2E * vf;
            u16* Zr = &ZT[(d * 32 + h) * 248];
            u16* Fr = &FT[(d * 32 + h) * 248];
            if (d == 0) chain_run<0>(Zr, Fr, kf, bf_);
            else        chain_run<1>(Zr, Fr, kf, bf_);
        }
        __syncthreads();

        // h-phase (parallel) + one-time guard zero
        if (lay == 0) {
            for (int i = tid; i < 21 * 72; i += 512) {
                int r = i / 72, ci = i - r * 72;
                int row = r < 7 ? r : (TnN + r);
                Hs[row * 72 + ci] = 0;
            }
        }
        for (int task = tid; task < 1984; task += 512) {
            int h = task & 31, d = (task >> 5) & 1, grp = task >> 6;
            int gb = grp * 8;
            const float vr_ = vv[d * 64 + 32 + h], br_ = bv[d * 64 + 32 + h];
            const float kr = -LOG2E * vr_;
            const u16* Cr = &ZT[(d * 32 + h) * 248];
            bf16x8 c8 = *(const bf16x8*)&Cr[gb];
            float cl[8];
            #pragma unroll
            for (int k = 0; k < 8; ++k) cl[k] = (float)c8[k];
            #pragma unroll
            for (int k = 0; k < 8; ++k) {
                int t = gb + k;
                if (t < TnN) {
                    float cpr;
                    if (d == 0) cpr = (t == 0) ? 0.f : (k ? cl[k - 1] : bf2f(Cr[gb - 1]));
                    else        cpr = (t == TnN - 1) ? 0.f : (k < 7 ? cl[k + 1] : bf2f(Cr[gb + 8]));
                    float ur = bf2f(Rs[d * 7776 + t * 32 + h]);
                    float ux = bf2f(Xs[d * 7776 + t * 32 + h]);
                    float xr = fmaf(kr, cpr, -LOG2E * (ur + br_));
                    float rg = __builtin_amdgcn_rcpf(1.f + hw_exp2(xr));
                    float hv = fmaf(rg, cl[k] - ux, ux);
                    Hs[(t + 7) * 72 + d * 32 + h] = f2bf(hv);
                }
            }
        }
        __syncthreads();
    }

    // ---- conv phase: A = Hs, scratch in dead ZT+ region ----
    {
        const int b = n >> 7, f = n & 127;
        u16* Bs = sh + ZT0;                       // 64 x 40
        float* Cf = (float*)(sh + ZT0 + 3072);    // 250 x 68 fp32
        f32x4 acc[2][4] = {};
        for (int kc = 0; kc < 16; ++kc) {
            int kk = kc >> 1, ci0 = (kc & 1) * 32;
            if (tid < 256) {
                int o = tid >> 2, grp = tid & 3;
                *(uint4*)&Bs[o * 40 + grp * 8] = *(const uint4*)&Wc[(size_t)o * 512 + kc * 32 + grp * 8];
            }
            __syncthreads();
            bf16x8 af[2], bfv[4];
            #pragma unroll
            for (int mt = 0; mt < 2; ++mt)
                af[mt] = *(const bf16x8*)&Hs[(w * 32 + mt * 16 + ml - kk + 7) * 72 + ci0 + q * 8];
            #pragma unroll
            for (int nt = 0; nt < 4; ++nt)
                bfv[nt] = *(const bf16x8*)&Bs[(nt * 16 + ml) * 40 + q * 8];
            #pragma unroll
            for (int mt = 0; mt < 2; ++mt)
                #pragma unroll
                for (int nt = 0; nt < 4; ++nt)
                    acc[mt][nt] = __builtin_amdgcn_mfma_f32_16x16x32_bf16(af[mt], bfv[nt], acc[mt][nt], 0, 0, 0);
            __syncthreads();
        }
        float bc[4];
        #pragma unroll
        for (int nt = 0; nt < 4; ++nt) bc[nt] = bct[nt * 16 + ml];
        #pragma unroll
        for (int mt = 0; mt < 2; ++mt)
            #pragma unroll
            for (int r = 0; r < 4; ++r) {
                int t = w * 32 + mt * 16 + q * 4 + r;
                if (t < Tt) {
                    #pragma unroll
                    for (int nt = 0; nt < 4; ++nt)
                        Cf[t * 68 + nt * 16 + ml] = acc[mt][nt][r] + bc[nt];
                }
            }
        __syncthreads();
        {
            const int sub = tid & 7;
            const int o = tid >> 3;               // 0..63, all channels in one pass
            const float* xrow = x + ((size_t)(b * 64 + o) * 128 + f) * Tt;
            float* orow = out + ((size_t)(b * 64 + o) * 128 + f) * Tt;
            #pragma unroll
            for (int it = 0; it < 16; ++it) {
                int j = it * 16 + sub * 2;
                if (j < Tt) {
                    float2 xv = *(const float2*)&xrow[j];
                    float2 ov;
                    ov.x = Cf[j * 68 + o] + xv.x;
                    ov.y = Cf[(j + 1) * 68 + o] + xv.y;
                    *(float2*)&orow[j] = ov;
                }
            }
        }
    }
}

extern "C" void kernel_launch(void* const* d_in, const int* in_sizes, int n_in,
                              void* d_out, int out_size, void* d_ws, size_t ws_size,
                              hipStream_t stream) {
    (void)in_sizes; (void)n_in; (void)out_size; (void)ws_size;
    const float* x     = (const float*)d_in[0];
    const float* gamma = (const float*)d_in[1];
    const float* beta  = (const float*)d_in[2];
    const float* W0    = (const float*)d_in[3];
    const float* Wr    = (const float*)d_in[4];
    const float* v     = (const float*)d_in[5];
    const float* bb    = (const float*)d_in[6];
    const float* wct   = (const float*)d_in[7];
    const float* bct   = (const float*)d_in[8];
    float* out = (float*)d_out;

    char* base = (char*)d_ws;
    float* stats = (float*)base;
    u16* W0k  = (u16*)(base + 256);                      // 262144 B  [8 k][256 j][64 c]
    u16* Wrt  = (u16*)(base + 256 + 262144);             // 98304 B
    u16* Wcto = (u16*)(base + 256 + 262144 + 98304);     // 65536 B
    u16* XbT  = (u16*)(base + 426240);                   // 8.39 MB   [256 n][256 t][64 c]

    hipMemsetAsync(stats, 0, 32, stream);
    k_stats<<<dim3(128, 2), 256, 0, stream>>>(x, stats);
    k_norm<<<dim3(256), 256, 0, stream>>>(x, stats, gamma, beta, XbT);
    k_packw<<<(212992 + 255) / 256, 256, 0, stream>>>(W0, Wr, wct, W0k, Wrt, Wcto);
    k_tail<<<dim3(256), 512, 0, stream>>>(XbT, W0k, Wrt, Wcto, v, bb, bct, x, out);
}

// Round 5
// 215.859 us; speedup vs baseline: 1.4591x; 1.0730x over previous
//
#include <hip/hip_runtime.h>
#include <math.h>

#define Tt 250
#define TnN 243
#define Nn 256
#define EPS_ 1e-5f
#define LOG2E 1.44269504f

typedef unsigned short u16;
typedef __bf16 bf16x8 __attribute__((ext_vector_type(8)));
typedef float f32x4 __attribute__((ext_vector_type(4)));

__device__ __forceinline__ u16 f2bf(float f) {
    unsigned u = __builtin_bit_cast(unsigned, f);
    u += 0x7FFFu + ((u >> 16) & 1u);
    return (u16)(u >> 16);
}
__device__ __forceinline__ float bf2f(u16 s) {
    unsigned u = ((unsigned)s) << 16;
    return __builtin_bit_cast(float, u);
}
__device__ __forceinline__ float hw_exp2(float x) {
    return __builtin_amdgcn_exp2f(x);
}

__device__ __forceinline__ void async_load16(const void* g, void* l) {
    __builtin_amdgcn_global_load_lds(
        (const __attribute__((address_space(1))) unsigned int*)g,
        (__attribute__((address_space(3))) unsigned int*)l, 16, 0, 0);
}

// DMA a [R][64-valid + 8-pad] u16 tile (gsrc contiguous R*64) into linear LDS rows of 72.
// 72 = 9 chunks of 8 u16; chunk sub==8 is pad (reads dummy). One 1024B segment per wave-call.
__device__ __forceinline__ void dma_pad72(const u16* gsrc, u16* ldst, int nseg, int w, int lane, int nw) {
    for (int seg = w; seg < nseg; seg += nw) {
        int c9 = seg * 64 + lane;
        int row = c9 / 9, sub = c9 - row * 9;
        const u16* src = (sub < 8) ? &gsrc[row * 64 + sub * 8] : gsrc;
        async_load16(src, ldst + seg * 512);
    }
}

// DMA conv-B: 64 rows x (32 valid + 8 pad) u16 from Wc[o*512 + coloff + ...]; 40 = 5 chunks.
__device__ __forceinline__ void dma_pad40(const u16* wc, int coloff, u16* ldst, int w, int lane) {
    for (int seg = w; seg < 5; seg += 16) {
        int c9 = seg * 64 + lane;
        int row = c9 / 5, sub = c9 - row * 5;
        const u16* src = (sub < 4) ? &wc[row * 512 + coloff + sub * 8] : wc;
        async_load16(src, ldst + seg * 512);
    }
}

// serial c-chain over one transposed row pair, direction D compile-time.
template<int D>
__device__ __forceinline__ void chain_run(u16* Zr, u16* Fr, float kf, float bf_) {
    bf16x8 z8 = *(const bf16x8*)&Zr[D ? 240 : 0];
    bf16x8 f8 = *(const bf16x8*)&Fr[D ? 240 : 0];
    float c = 0.f;
    for (int grp = 0; grp < 31; ++grp) {
        int gb = D ? (30 - grp) * 8 : grp * 8;
        bf16x8 zn = z8, fn = f8;
        if (grp < 30) {
            int gbn = D ? (29 - grp) * 8 : (grp + 1) * 8;
            zn = *(const bf16x8*)&Zr[gbn];
            fn = *(const bf16x8*)&Fr[gbn];
        }
        bf16x8 co;
        #pragma unroll
        for (int k = 0; k < 8; ++k) {
            const int idx = D ? (7 - k) : k;
            int t = gb + idx;
            float uz = (float)z8[idx];
            float af = -LOG2E * ((float)f8[idx] + bf_);
            float xe = fmaf(kf, c, af);
            float fg = __builtin_amdgcn_rcpf(1.f + hw_exp2(xe));
            float cn = fmaf(fg, c - uz, uz);
            bool ok = (t < TnN);
            if (ok) c = cn;
            co[idx] = ok ? (__bf16)c : (__bf16)0.f;
        }
        *(bf16x8*)&Zr[gb] = co;
        z8 = zn; f8 = fn;
    }
}

// ---------------- stats ----------------
__global__ void k_stats(const float* __restrict__ x, float* __restrict__ stats) {
    int b = blockIdx.y;
    const float* xb = x + (size_t)b * 64 * 128 * Tt;
    const int n = 64 * 128 * Tt;
    float s = 0.f, s2 = 0.f;
    for (int i = blockIdx.x * blockDim.x + threadIdx.x; i < n; i += gridDim.x * blockDim.x) {
        float v = xb[i];
        s += v; s2 += v * v;
    }
    for (int off = 32; off; off >>= 1) {
        s  += __shfl_down(s, off);
        s2 += __shfl_down(s2, off);
    }
    __shared__ float ls[8], ls2[8];
    int lane = threadIdx.x & 63, w = threadIdx.x >> 6;
    if (lane == 0) { ls[w] = s; ls2[w] = s2; }
    __syncthreads();
    if (threadIdx.x == 0) {
        float a = 0.f, a2 = 0.f;
        int nw = blockDim.x >> 6;
        for (int i = 0; i < nw; i++) { a += ls[i]; a2 += ls2[i]; }
        atomicAdd(&stats[b * 2 + 0], a);
        atomicAdd(&stats[b * 2 + 1], a2);
    }
}

// ---------------- normalize + transpose -> bf16 XbT[n][256 t][64 c] ----------------
__global__ __launch_bounds__(512) void k_norm(const float* __restrict__ x, const float* __restrict__ stats,
                       const float* __restrict__ gamma, const float* __restrict__ beta,
                       u16* __restrict__ xbt) {
    __shared__ u16 lt[64 * 260];
    const int n = blockIdx.x, tid = threadIdx.x;
    const int b = n >> 7, f = n & 127;
    const float inv = 1.0f / (float)(64 * 128 * Tt);
    float mean = stats[b * 2 + 0] * inv;
    float var  = stats[b * 2 + 1] * inv - mean * mean;
    float rstd = rsqrtf(var + EPS_);
    const int c = tid >> 3, vq = tid & 7;
    const float gm = gamma[c] * rstd;
    const float bt = beta[c] - mean * gm;
    const float* xr = x + ((size_t)(b * 64 + c) * 128 + f) * Tt;
    #pragma unroll
    for (int j = 0; j < 16; ++j) {
        int t0 = vq * 2 + j * 16;        // even t, 0..254
        unsigned pv = 0u;
        if (t0 < Tt) {
            float2 xv = *(const float2*)&xr[t0];
            pv = (unsigned)f2bf(fmaf(xv.x, gm, bt)) | ((unsigned)f2bf(fmaf(xv.y, gm, bt)) << 16);
        }
        *(unsigned*)&lt[c * 260 + t0] = pv;   // zeros for t >= 250
    }
    __syncthreads();
    const int cg = tid & 7, tq = tid >> 3;   // tq 0..63
    #pragma unroll
    for (int it = 0; it < 4; ++it) {
        int t = it * 64 + tq;
        u16 tmp[8];
        #pragma unroll
        for (int jj = 0; jj < 8; ++jj) tmp[jj] = lt[(cg * 8 + jj) * 260 + t];
        uint4 o;
        o.x = (unsigned)tmp[0] | ((unsigned)tmp[1] << 16);
        o.y = (unsigned)tmp[2] | ((unsigned)tmp[3] << 16);
        o.z = (unsigned)tmp[4] | ((unsigned)tmp[5] << 16);
        o.w = (unsigned)tmp[6] | ((unsigned)tmp[7] << 16);
        *(uint4*)&xbt[(size_t)n * 16384 + t * 64 + cg * 8] = o;
    }
}

// ---------------- pack weights ----------------
// W0k[k][j][c] = W0[d = j>>7][c*8+k][j&127]
__global__ void k_packw(const float* __restrict__ W0, const float* __restrict__ Wr,
                        const float* __restrict__ wct,
                        u16* __restrict__ W0k, u16* __restrict__ Wrt, u16* __restrict__ Wcto) {
    int idx = blockIdx.x * blockDim.x + threadIdx.x;
    if (idx < 131072) {
        int k = idx >> 14, j = (idx >> 6) & 255, c = idx & 63;
        int d = j >> 7, ck = c * 8 + k;
        W0k[idx] = f2bf(W0[((size_t)d * 512 + ck) * 128 + (j & 127)]);
    } else if (idx < 180224) {
        int r = idx - 131072;
        int i = r & 63, j = (r >> 6) & 255, lidx = r >> 14;
        Wrt[r] = f2bf(Wr[(size_t)(lidx * 2 + (j >> 7)) * 8192 + i * 128 + (j & 127)]);
    } else if (idx < 212992) {
        int r = idx - 180224;
        int o = r >> 9; int k = r & 511; int kk = k >> 6, ci = k & 63;
        Wcto[r] = f2bf(wct[(size_t)ci * 512 + o * 8 + kk]);
    }
}

// GEMM epilogue (16-wave): acc[16] -> ZT/FT (transposed [h][t]) and Rs/Xs ([t][h] planes)
__device__ __forceinline__ void epi16(f32x4 (&acc)[16], u16* ZT, u16* FT, u16* Rs, u16* Xs,
                                      int w, int ml, int q) {
    int t0 = w * 16 + q * 4;
    if (t0 >= TnN) return;
    bool vec = (t0 + 4 <= TnN);
    #pragma unroll
    for (int nt = 0; nt < 16; ++nt) {
        int d2 = nt >> 3, g2 = (nt >> 1) & 3, hh = (nt & 1) * 16 + ml;
        if (g2 < 2) {
            u16* P = (g2 ? FT : ZT) + (d2 * 32 + hh) * 248;
            if (vec) {
                uint2 pv;
                pv.x = (unsigned)f2bf(acc[nt][0]) | ((unsigned)f2bf(acc[nt][1]) << 16);
                pv.y = (unsigned)f2bf(acc[nt][2]) | ((unsigned)f2bf(acc[nt][3]) << 16);
                *(uint2*)&P[t0] = pv;
            } else {
                #pragma unroll
                for (int r = 0; r < 4; ++r) {
                    int t = t0 + r;
                    if (t < TnN) P[t] = f2bf(acc[nt][r]);
                }
            }
        } else {
            u16* P = (g2 == 2 ? Rs : Xs) + d2 * 7776 + hh;
            #pragma unroll
            for (int r = 0; r < 4; ++r) {
                int t = t0 + r;
                if (t < TnN) P[t * 32] = f2bf(acc[nt][r]);
            }
        }
    }
}

// ---------------- mega tail (1024 threads / 16 waves) ----------------
// LDS map (u16 offsets): Hs 0..19007 (264x72), ZT 19008 (64x248), FT 34880 (64x248),
//                        Rs 50752 (2x243x32), Xs 66304 (2x243x32). Total 81856 u16 = 163,712 B
// lay0: Hs holds XbT tile [256][72]; B dbuf at ZT0 / ZT0+18432 (dead ZT/FT/Rs span).
#define HS0 0
#define ZT0 19008
#define FT0 34880
#define RS0 50752
#define XS0 66304
#define SH_U16 81856
__global__ __launch_bounds__(1024) void k_tail(const u16* __restrict__ XbT,
                                               const u16* __restrict__ W0k,
                                               const u16* __restrict__ Wrt,
                                               const u16* __restrict__ Wc,
                                               const float* __restrict__ v,
                                               const float* __restrict__ bbias,
                                               const float* __restrict__ bct,
                                               const float* __restrict__ x,
                                               float* __restrict__ out) {
    __shared__ __align__(16) u16 sh[SH_U16];
    u16* Hs = sh + HS0;
    u16* ZT = sh + ZT0;
    u16* FT = sh + FT0;
    u16* Rs = sh + RS0;
    u16* Xs = sh + XS0;
    const int tid = threadIdx.x;
    const int n = blockIdx.x;
    const int lane = tid & 63, w = tid >> 6;          // w in 0..15
    const int ml = lane & 15, q = lane >> 4;

    for (int lay = 0; lay < 4; ++lay) {
        if (lay == 0) {
            // ---- fused layer-0 GEMM: acc[t][j] = sum_k sum_c XbT[n][t+k][c] * W0k[k][j][c]
            const u16* Xn = XbT + (size_t)n * 16384;
            u16* Bb0 = sh + ZT0;                        // 256x72 u16 each, dbuf
            u16* Bb1 = sh + ZT0 + 18432;
            dma_pad72(Xn, Hs, 36, w, lane, 16);         // A tile -> Hs rows 0..255
            dma_pad72(W0k, Bb0, 36, w, lane, 16);       // B k=0
            __syncthreads();                            // drains DMA
            f32x4 acc[16];
            #pragma unroll
            for (int nt = 0; nt < 16; ++nt) acc[nt] = (f32x4){0.f, 0.f, 0.f, 0.f};
            #pragma unroll
            for (int k = 0; k < 8; ++k) {
                u16* Bl = (k & 1) ? Bb1 : Bb0;
                if (k < 7)                               // async prefetch k+1; drained by barrier below
                    dma_pad72(W0k + (size_t)(k + 1) * 16384, (k & 1) ? Bb0 : Bb1, 36, w, lane, 16);
                #pragma unroll
                for (int c2 = 0; c2 < 2; ++c2) {
                    int c0 = c2 * 32;
                    bf16x8 af = *(const bf16x8*)&Hs[(w * 16 + ml + k) * 72 + c0 + q * 8];
                    #pragma unroll
                    for (int nt = 0; nt < 16; ++nt) {
                        bf16x8 bfr = *(const bf16x8*)&Bl[(nt * 16 + ml) * 72 + c0 + q * 8];
                        acc[nt] = __builtin_amdgcn_mfma_f32_16x16x32_bf16(af, bfr, acc[nt], 0, 0, 0);
                    }
                }
                __syncthreads();
            }
            epi16(acc, ZT, FT, Rs, Xs, w, ml, q);
            __syncthreads();
        } else {
            // recurrent GEMM: B tile [256 j][64 c] DMA'd into padded Bst (dead ZT/FT span)
            u16* Bst = sh + ZT0;                         // 256x72
            const u16* Wl = Wrt + (size_t)(lay - 1) * 16384;
            dma_pad72(Wl, Bst, 36, w, lane, 16);
            __syncthreads();                             // drains DMA; Hs ready from h-phase
            f32x4 acc[16];
            #pragma unroll
            for (int nt = 0; nt < 16; ++nt) acc[nt] = (f32x4){0.f, 0.f, 0.f, 0.f};
            #pragma unroll
            for (int c2 = 0; c2 < 2; ++c2) {
                int c0 = c2 * 32;
                bf16x8 af = *(const bf16x8*)&Hs[(w * 16 + ml + 7) * 72 + c0 + q * 8];
                #pragma unroll
                for (int nt = 0; nt < 16; ++nt) {
                    bf16x8 bfr = *(const bf16x8*)&Bst[(nt * 16 + ml) * 72 + c0 + q * 8];
                    acc[nt] = __builtin_amdgcn_mfma_f32_16x16x32_bf16(af, bfr, acc[nt], 0, 0, 0);
                }
            }
            __syncthreads();   // all B reads done -> ZT/FT writable
            epi16(acc, ZT, FT, Rs, Xs, w, ml, q);
            __syncthreads();
        }

        const float* vv = v + (size_t)(lay * 2) * 64;
        const float* bv = bbias + (size_t)(lay * 2) * 64;

        // serial c-chains: wave0 d0 (forward), wave1 d1 (backward)
        if (w < 2 && lane < 32) {
            const int d = w, h = lane;
            const float vf = vv[d * 64 + h], bf_ = bv[d * 64 + h];
            const float kf = -LOG2E * vf;
            u16* Zr = &ZT[(d * 32 + h) * 248];
            u16* Fr = &FT[(d * 32 + h) * 248];
            if (d == 0) chain_run<0>(Zr, Fr, kf, bf_);
            else        chain_run<1>(Zr, Fr, kf, bf_);
        }
        __syncthreads();

        // h-phase (parallel) + one-time guard zero
        if (lay == 0) {
            for (int i = tid; i < 21 * 72; i += 1024) {
                int r = i / 72, ci = i - r * 72;
                int row = r < 7 ? r : (TnN + r);
                Hs[row * 72 + ci] = 0;
            }
        }
        for (int task = tid; task < 1984; task += 1024) {
            int h = task & 31, d = (task >> 5) & 1, grp = task >> 6;
            int gb = grp * 8;
            const float vr_ = vv[d * 64 + 32 + h], br_ = bv[d * 64 + 32 + h];
            const float kr = -LOG2E * vr_;
            const u16* Cr = &ZT[(d * 32 + h) * 248];
            bf16x8 c8 = *(const bf16x8*)&Cr[gb];
            float cl[8];
            #pragma unroll
            for (int k = 0; k < 8; ++k) cl[k] = (float)c8[k];
            #pragma unroll
            for (int k = 0; k < 8; ++k) {
                int t = gb + k;
                if (t < TnN) {
                    float cpr;
                    if (d == 0) cpr = (t == 0) ? 0.f : (k ? cl[k - 1] : bf2f(Cr[gb - 1]));
                    else        cpr = (t == TnN - 1) ? 0.f : (k < 7 ? cl[k + 1] : bf2f(Cr[gb + 8]));
                    float ur = bf2f(Rs[d * 7776 + t * 32 + h]);
                    float ux = bf2f(Xs[d * 7776 + t * 32 + h]);
                    float xr = fmaf(kr, cpr, -LOG2E * (ur + br_));
                    float rg = __builtin_amdgcn_rcpf(1.f + hw_exp2(xr));
                    float hv = fmaf(rg, cl[k] - ux, ux);
                    Hs[(t + 7) * 72 + d * 32 + h] = f2bf(hv);
                }
            }
        }
        __syncthreads();
    }

    // ---- conv phase: A = Hs, B DMA-double-buffered, 1 barrier/kc ----
    {
        const int b = n >> 7, f = n & 127;
        u16* Bs0 = sh + ZT0;                      // 64x40 each
        u16* Bs1 = sh + ZT0 + 2560;
        float* Cf = (float*)(sh + ZT0 + 5120);    // 250 x 68 fp32 (dead FT/Rs span)
        f32x4 acc[4] = {};
        dma_pad40(Wc, 0, Bs0, w, lane);
        __syncthreads();
        #pragma unroll
        for (int kc = 0; kc < 16; ++kc) {
            int kk = kc >> 1, ci0 = (kc & 1) * 32;
            if (kc < 15)
                dma_pad40(Wc, (kc + 1) * 32, (kc & 1) ? Bs0 : Bs1, w, lane);
            u16* Bl = (kc & 1) ? Bs1 : Bs0;
            bf16x8 af = *(const bf16x8*)&Hs[(w * 16 + ml - kk + 7) * 72 + ci0 + q * 8];
            #pragma unroll
            for (int nt = 0; nt < 4; ++nt) {
                bf16x8 bfv = *(const bf16x8*)&Bl[(nt * 16 + ml) * 40 + q * 8];
                acc[nt] = __builtin_amdgcn_mfma_f32_16x16x32_bf16(af, bfv, acc[nt], 0, 0, 0);
            }
            __syncthreads();
        }
        float bc[4];
        #pragma unroll
        for (int nt = 0; nt < 4; ++nt) bc[nt] = bct[nt * 16 + ml];
        #pragma unroll
        for (int r = 0; r < 4; ++r) {
            int t = w * 16 + q * 4 + r;
            if (t < Tt) {
                #pragma unroll
                for (int nt = 0; nt < 4; ++nt)
                    Cf[t * 68 + nt * 16 + ml] = acc[nt][r] + bc[nt];
            }
        }
        __syncthreads();
        {
            const int sub = tid & 15;
            const int o = tid >> 4;               // 0..63
            const float* xrow = x + ((size_t)(b * 64 + o) * 128 + f) * Tt;
            float* orow = out + ((size_t)(b * 64 + o) * 128 + f) * Tt;
            #pragma unroll
            for (int it = 0; it < 8; ++it) {
                int j = it * 32 + sub * 2;
                if (j < Tt) {
                    float2 xv = *(const float2*)&xrow[j];
                    float2 ov;
                    ov.x = Cf[j * 68 + o] + xv.x;
                    ov.y = Cf[(j + 1) * 68 + o] + xv.y;
                    *(float2*)&orow[j] = ov;
                }
            }
        }
    }
}

extern "C" void kernel_launch(void* const* d_in, const int* in_sizes, int n_in,
                              void* d_out, int out_size, void* d_ws, size_t ws_size,
                              hipStream_t stream) {
    (void)in_sizes; (void)n_in; (void)out_size; (void)ws_size;
    const float* x     = (const float*)d_in[0];
    const float* gamma = (const float*)d_in[1];
    const float* beta  = (const float*)d_in[2];
    const float* W0    = (const float*)d_in[3];
    const float* Wr    = (const float*)d_in[4];
    const float* v     = (const float*)d_in[5];
    const float* bb    = (const float*)d_in[6];
    const float* wct   = (const float*)d_in[7];
    const float* bct   = (const float*)d_in[8];
    float* out = (float*)d_out;

    char* base = (char*)d_ws;
    float* stats = (float*)base;
    u16* W0k  = (u16*)(base + 256);                      // 262144 B  [8 k][256 j][64 c]
    u16* Wrt  = (u16*)(base + 256 + 262144);             // 98304 B
    u16* Wcto = (u16*)(base + 256 + 262144 + 98304);     // 65536 B
    u16* XbT  = (u16*)(base + 426240);                   // 8.39 MB   [256 n][256 t][64 c]

    hipMemsetAsync(stats, 0, 32, stream);
    k_stats<<<dim3(128, 2), 256, 0, stream>>>(x, stats);
    k_norm<<<dim3(256), 512, 0, stream>>>(x, stats, gamma, beta, XbT);
    k_packw<<<(212992 + 255) / 256, 256, 0, stream>>>(W0, Wr, wct, W0k, Wrt, Wcto);
    k_tail<<<dim3(256), 1024, 0, stream>>>(XbT, W0k, Wrt, Wcto, v, bb, bct, x, out);
}